// Round 6
// baseline (449.326 us; speedup 1.0000x reference)
//
#include <hip/hip_runtime.h>
#include <hip/hip_fp16.h>

// GIN forward, round 19: MORE FUSION (delete staging round-trips).
// Baseline R18 (263us). Changes:
//   1. g64gg_k: layer-0 gather fused INTO the gg00 tile kernel (gathers
//      32 nodes x 64-wide straight into the LDS A-tile). sb buffer and
//      its 12.8MB round-trip deleted; one dispatch fewer.
//   2. gpool_k: final gather fused with mean-pool via fire-and-forget
//      fp32 atomicAdd into pool_sums[graph][col] (512KB, zeroed in prep).
//      h tensor and its 25.6MB round-trip deleted. post_k divides by
//      count and runs the post-MLP.
// CSR build unchanged (rank-based atomic-free fill, R17 win). fgg_k
// unchanged (R18 win). Gather inner loop unchanged (R2: ILP-neutral).

#define N_NODES  50000
#define N_EDGES  600000
#define N_FEAT   64
#define DIM      128
#define N_GRAPHS 1024
#define NC       7           // src chunks: src>>13, 0..6
#define CSH      13
#define TOT2     (N_NODES * NC)          // 350000 bins
#define SCH      2048                    // scan elems per block
#define NBLK     ((TOT2 + SCH - 1) / SCH)  // 171
#define TPB      256
#define GT32     ((N_NODES + 31) / 32)     // 1563 fused tiles

typedef _Float16 f16x8 __attribute__((ext_vector_type(8)));
typedef float    f32x4 __attribute__((ext_vector_type(4)));

#define CNTZ2 (TOT2 / 4)                 // 87500 int4 items
#define PSZ4  (N_GRAPHS * DIM / 4)       // 32768 int4 items (pool_sums)
#define XWORK (N_NODES * N_FEAT / 4)
#define PREP_TOTAL (CNTZ2 + PSZ4 + XWORK + N_FEAT * DIM + 3 * DIM * DIM)

// ---- prep: zero cnt2+pool_sums ; x->fp16 ; W[K][128] -> Wt[128][K] ----
__global__ __launch_bounds__(TPB) void prep_k(
    const float* __restrict__ x, __half* __restrict__ xh,
    const float* __restrict__ w0, const float* __restrict__ w1,
    const float* __restrict__ w2, const float* __restrict__ w3,
    __half* __restrict__ Wt0, __half* __restrict__ Wt1,
    __half* __restrict__ Wt2, __half* __restrict__ Wt3,
    int* __restrict__ cnt2, int* __restrict__ pool_sums) {
  int i = blockIdx.x * TPB + threadIdx.x;
  if (i < CNTZ2) {
    *reinterpret_cast<int4*>(cnt2 + i * 4) = make_int4(0, 0, 0, 0);
    return;
  }
  i -= CNTZ2;
  if (i < PSZ4) {
    *reinterpret_cast<int4*>(pool_sums + i * 4) = make_int4(0, 0, 0, 0);
    return;
  }
  i -= PSZ4;
  if (i < XWORK) {
    float4 v = *reinterpret_cast<const float4*>(x + (size_t)i * 4);
    union { __half2 h2[2]; uint2 u; } pk;
    pk.h2[0] = __floats2half2_rn(v.x, v.y);
    pk.h2[1] = __floats2half2_rn(v.z, v.w);
    *reinterpret_cast<uint2*>(xh + (size_t)i * 4) = pk.u;
    return;
  }
  int j = i - XWORK;
  if (j < N_FEAT * DIM) {
    int k = j >> 7, n = j & 127;
    Wt0[n * N_FEAT + k] = __float2half(w0[j]);
    return;
  }
  j -= N_FEAT * DIM;
  if (j >= 3 * DIM * DIM) return;
  int wsel = j / (DIM * DIM);
  int jj = j - wsel * (DIM * DIM);
  int k = jj >> 7, n = jj & 127;
  const float* W = (wsel == 0) ? w1 : (wsel == 1) ? w2 : w3;
  __half* Wt     = (wsel == 0) ? Wt1 : (wsel == 1) ? Wt2 : Wt3;
  Wt[n * DIM + k] = __float2half(W[jj]);
}

// ---- histogram over (dst, src-chunk) keys; rank[e] = old count ----
__global__ __launch_bounds__(TPB) void hist_k(
    const int* __restrict__ src, const int* __restrict__ dst,
    int* __restrict__ cnt2, int* __restrict__ rank) {
  int e = blockIdx.x * TPB + threadIdx.x;
  if (e >= N_EDGES) return;
  int key = dst[e] * NC + (src[e] >> CSH);
  rank[e] = atomicAdd(&cnt2[key], 1);
}

// ---- scan phase 1: per-block (2048 elems) partial sums ----
__global__ __launch_bounds__(TPB) void scan_part_k(
    const int* __restrict__ cnt2, int* __restrict__ part) {
  __shared__ int ws[4];
  int t = threadIdx.x, b = blockIdx.x;
  int base = b * SCH + t * 8;
  int s = 0;
  if (base < TOT2) {    // TOT2 % 8 == 0: all 8 in-bounds together
    int4 a = *reinterpret_cast<const int4*>(cnt2 + base);
    int4 c = *reinterpret_cast<const int4*>(cnt2 + base + 4);
    s = a.x + a.y + a.z + a.w + c.x + c.y + c.z + c.w;
  }
  for (int off = 32; off; off >>= 1) s += __shfl_down(s, off, 64);
  int lane = t & 63, wv = t >> 6;
  if (lane == 0) ws[wv] = s;
  __syncthreads();
  if (t == 0) part[b] = ws[0] + ws[1] + ws[2] + ws[3];
}

// ---- scan phase 2: LDS scan of NBLK partials + intra-block scan-write ----
__global__ __launch_bounds__(TPB) void scan_write_k(
    const int* __restrict__ cnt2, const int* __restrict__ part,
    int* __restrict__ row_ptr2) {
  __shared__ int pscan[TPB];
  __shared__ int wsum[4];
  int t = threadIdx.x, b = blockIdx.x;
  int lane = t & 63, wv = t >> 6;
  int base = b * SCH + t * 8;

  pscan[t] = (t < NBLK) ? part[t] : 0;
  __syncthreads();
  for (int off = 1; off < TPB; off <<= 1) {
    int v = (t >= off) ? pscan[t - off] : 0;
    __syncthreads();
    pscan[t] += v;
    __syncthreads();
  }
  int blk_off = (b > 0) ? pscan[b - 1] : 0;

  int v[8] = {0,0,0,0,0,0,0,0};
  if (base < TOT2) {
    int4 a = *reinterpret_cast<const int4*>(cnt2 + base);
    int4 c = *reinterpret_cast<const int4*>(cnt2 + base + 4);
    v[0]=a.x; v[1]=a.y; v[2]=a.z; v[3]=a.w;
    v[4]=c.x; v[5]=c.y; v[6]=c.z; v[7]=c.w;
  }
  int ls = 0;
#pragma unroll
  for (int i = 0; i < 8; ++i) ls += v[i];
  int incl = ls;
  for (int off = 1; off < 64; off <<= 1) {
    int u = __shfl_up(incl, off, 64);
    if (lane >= off) incl += u;
  }
  if (lane == 63) wsum[wv] = incl;
  __syncthreads();
  int woff = 0;
  for (int w = 0; w < wv; ++w) woff += wsum[w];
  int run = blk_off + woff + (incl - ls);
  if (base < TOT2) {
    int rp[8];
#pragma unroll
    for (int i = 0; i < 8; ++i) { rp[i] = run; run += v[i]; }
    *reinterpret_cast<int4*>(row_ptr2 + base) = make_int4(rp[0], rp[1], rp[2], rp[3]);
    *reinterpret_cast<int4*>(row_ptr2 + base + 4) = make_int4(rp[4], rp[5], rp[6], rp[7]);
  }
  if (b == 0 && t == 0) row_ptr2[TOT2] = N_EDGES;
}

// ---- fill: atomic-free. pos = row_ptr2[key] + rank[e] ----
__global__ __launch_bounds__(TPB) void fill_k(
    const int* __restrict__ src, const int* __restrict__ dst,
    const int* __restrict__ row_ptr2, const int* __restrict__ rank,
    int* __restrict__ csr_src) {
  int e = blockIdx.x * TPB + threadIdx.x;
  if (e >= N_EDGES) return;
  int s = src[e];
  int key = dst[e] * NC + (s >> CSH);
  csr_src[row_ptr2[key] + rank[e]] = s;
}

// ---- g64gg: per 32-row tile: gather64 -> As; h0 = relu(As@W0+b0);
//      y1 = h0@W1. B-fragments straight from L2-hot Wt. LDS 13.3KB. ----
__global__ __launch_bounds__(TPB) void g64gg_k(
    const __half* __restrict__ xh, const int* __restrict__ row_ptr2,
    const int* __restrict__ csr_src,
    const __half* __restrict__ Wt0, const float* __restrict__ b0,
    const __half* __restrict__ Wt1, __half* __restrict__ y1) {
  __shared__ __align__(16) __half As[32][72];   // gathered s tile (K=64)
  __shared__ __align__(16) __half Hs[32][136];  // h0 tile, reused as Os
  const f16x8* xv = reinterpret_cast<const f16x8*>(xh);
  int tid = threadIdx.x;
  int row0 = blockIdx.x * 32;

  // gather phase: 32 node-slots x 8 feature-lanes (64-wide)
  {
    int ns = tid >> 3, l = tid & 7;
    int node = row0 + ns;
    f16x8 o;
    if (node < N_NODES) {
      int beg = row_ptr2[node * NC];
      int end = row_ptr2[node * NC + NC];
      f16x8 self = xv[(size_t)node * 8 + l];
      float acc[8];
#pragma unroll
      for (int v = 0; v < 8; ++v) acc[v] = (float)self[v];
      int e = beg;
      for (; e + 3 < end; e += 4) {
        int s0 = csr_src[e+0], s1 = csr_src[e+1], s2 = csr_src[e+2], s3 = csr_src[e+3];
        f16x8 v0 = xv[(size_t)s0 * 8 + l];
        f16x8 v1 = xv[(size_t)s1 * 8 + l];
        f16x8 v2 = xv[(size_t)s2 * 8 + l];
        f16x8 v3 = xv[(size_t)s3 * 8 + l];
#pragma unroll
        for (int v = 0; v < 8; ++v)
          acc[v] += ((float)v0[v] + (float)v1[v]) + ((float)v2[v] + (float)v3[v]);
      }
      for (; e < end; ++e) {
        f16x8 v0 = xv[(size_t)csr_src[e] * 8 + l];
#pragma unroll
        for (int v = 0; v < 8; ++v) acc[v] += (float)v0[v];
      }
#pragma unroll
      for (int v = 0; v < 8; ++v) o[v] = (_Float16)acc[v];
    } else {
#pragma unroll
      for (int v = 0; v < 8; ++v) o[v] = (_Float16)0.f;
    }
    *reinterpret_cast<f16x8*>(&As[ns][l * 8]) = o;
  }
  __syncthreads();

  int w = tid >> 6, lane = tid & 63;
  int quad = lane >> 4, m = lane & 15;
  int col0 = w * 32;

  // phase A: h0 = relu(As @ W0 + b0)  (K=64)
  f32x4 accA[2][2];
#pragma unroll
  for (int mt = 0; mt < 2; ++mt)
#pragma unroll
    for (int nt = 0; nt < 2; ++nt) accA[mt][nt] = (f32x4){0.f,0.f,0.f,0.f};
#pragma unroll
  for (int kc = 0; kc < 2; ++kc) {
    f16x8 a0 = *reinterpret_cast<const f16x8*>(&As[m][kc*32 + quad*8]);
    f16x8 a1 = *reinterpret_cast<const f16x8*>(&As[16 + m][kc*32 + quad*8]);
#pragma unroll
    for (int nt = 0; nt < 2; ++nt) {
      f16x8 b = *reinterpret_cast<const f16x8*>(
          Wt0 + (size_t)(col0 + nt*16 + m) * N_FEAT + kc*32 + quad*8);
      accA[0][nt] = __builtin_amdgcn_mfma_f32_16x16x32_f16(a0, b, accA[0][nt], 0, 0, 0);
      accA[1][nt] = __builtin_amdgcn_mfma_f32_16x16x32_f16(a1, b, accA[1][nt], 0, 0, 0);
    }
  }
#pragma unroll
  for (int mt = 0; mt < 2; ++mt)
#pragma unroll
    for (int nt = 0; nt < 2; ++nt) {
      float bv = b0[col0 + nt*16 + m];
#pragma unroll
      for (int r = 0; r < 4; ++r)
        Hs[mt*16 + quad*4 + r][col0 + nt*16 + m] =
            __float2half(fmaxf(accA[mt][nt][r] + bv, 0.f));
    }
  __syncthreads();

  // phase B: y1 = Hs @ W1  (K=128)
  f32x4 accB[2][2];
#pragma unroll
  for (int mt = 0; mt < 2; ++mt)
#pragma unroll
    for (int nt = 0; nt < 2; ++nt) accB[mt][nt] = (f32x4){0.f,0.f,0.f,0.f};
#pragma unroll
  for (int kc = 0; kc < 4; ++kc) {
    f16x8 a0 = *reinterpret_cast<const f16x8*>(&Hs[m][kc*32 + quad*8]);
    f16x8 a1 = *reinterpret_cast<const f16x8*>(&Hs[16 + m][kc*32 + quad*8]);
#pragma unroll
    for (int nt = 0; nt < 2; ++nt) {
      f16x8 b = *reinterpret_cast<const f16x8*>(
          Wt1 + (size_t)(col0 + nt*16 + m) * DIM + kc*32 + quad*8);
      accB[0][nt] = __builtin_amdgcn_mfma_f32_16x16x32_f16(a0, b, accB[0][nt], 0, 0, 0);
      accB[1][nt] = __builtin_amdgcn_mfma_f32_16x16x32_f16(a1, b, accB[1][nt], 0, 0, 0);
    }
  }
  __syncthreads();   // Hs reads done -> reuse as Os
#pragma unroll
  for (int mt = 0; mt < 2; ++mt)
#pragma unroll
    for (int nt = 0; nt < 2; ++nt)
#pragma unroll
      for (int r = 0; r < 4; ++r)
        Hs[mt*16 + quad*4 + r][col0 + nt*16 + m] = __float2half(accB[mt][nt][r]);
  __syncthreads();
#pragma unroll
  for (int it = 0; it < 2; ++it) {
    int i = tid + it * TPB;
    int r = i >> 4, c = (i & 15) * 8;
    int row = row0 + r;
    if (row < N_NODES)
      *reinterpret_cast<f16x8*>(y1 + (size_t)row * DIM + c) =
          *reinterpret_cast<const f16x8*>(&Hs[r][c]);
  }
}

// ---- fgg: per 32-row tile: h' = relu(y + agg(y) + b); y' = h' @ Wn ----
__global__ __launch_bounds__(TPB) void fgg_k(
    const __half* __restrict__ y, const int* __restrict__ row_ptr2,
    const int* __restrict__ csr_src, const float* __restrict__ bias,
    const __half* __restrict__ Wn, __half* __restrict__ yout) {
  __shared__ __align__(16) __half As[32][136];  // h' tile, reused as Os
  const f16x8* yv = reinterpret_cast<const f16x8*>(y);
  int tid = threadIdx.x;
  int row0 = blockIdx.x * 32;
  int g = tid >> 4, l = tid & 15;   // 16 node-slots x 16 feature-lanes

#pragma unroll 1
  for (int p = 0; p < 2; ++p) {
    int node = row0 + p * 16 + g;
    if (node < N_NODES) {
      int beg = row_ptr2[node * NC];
      int end = row_ptr2[node * NC + NC];
      f16x8 self = yv[(size_t)node * 16 + l];
      float acc[8];
#pragma unroll
      for (int v = 0; v < 8; ++v) acc[v] = (float)self[v];
      int e = beg;
      for (; e + 3 < end; e += 4) {
        int s0 = csr_src[e+0], s1 = csr_src[e+1], s2 = csr_src[e+2], s3 = csr_src[e+3];
        f16x8 v0 = yv[(size_t)s0 * 16 + l];
        f16x8 v1 = yv[(size_t)s1 * 16 + l];
        f16x8 v2 = yv[(size_t)s2 * 16 + l];
        f16x8 v3 = yv[(size_t)s3 * 16 + l];
#pragma unroll
        for (int v = 0; v < 8; ++v)
          acc[v] += ((float)v0[v] + (float)v1[v]) + ((float)v2[v] + (float)v3[v]);
      }
      for (; e < end; ++e) {
        f16x8 v0 = yv[(size_t)csr_src[e] * 16 + l];
#pragma unroll
        for (int v = 0; v < 8; ++v) acc[v] += (float)v0[v];
      }
      float4 bb0 = *reinterpret_cast<const float4*>(bias + l * 8);
      float4 bb1 = *reinterpret_cast<const float4*>(bias + l * 8 + 4);
      float bb[8] = {bb0.x, bb0.y, bb0.z, bb0.w, bb1.x, bb1.y, bb1.z, bb1.w};
      f16x8 o;
#pragma unroll
      for (int v = 0; v < 8; ++v) o[v] = (_Float16)fmaxf(acc[v] + bb[v], 0.f);
      *reinterpret_cast<f16x8*>(&As[p * 16 + g][l * 8]) = o;
    }
  }
  __syncthreads();

  int w = tid >> 6, lane = tid & 63;
  int quad = lane >> 4, m = lane & 15;
  int col0 = w * 32;
  f32x4 acc2[2][2];
#pragma unroll
  for (int mt = 0; mt < 2; ++mt)
#pragma unroll
    for (int nt = 0; nt < 2; ++nt) acc2[mt][nt] = (f32x4){0.f,0.f,0.f,0.f};
#pragma unroll
  for (int kc = 0; kc < 4; ++kc) {
    f16x8 a0 = *reinterpret_cast<const f16x8*>(&As[m][kc*32 + quad*8]);
    f16x8 a1 = *reinterpret_cast<const f16x8*>(&As[16 + m][kc*32 + quad*8]);
#pragma unroll
    for (int nt = 0; nt < 2; ++nt) {
      f16x8 b = *reinterpret_cast<const f16x8*>(
          Wn + (size_t)(col0 + nt*16 + m) * DIM + kc*32 + quad*8);
      acc2[0][nt] = __builtin_amdgcn_mfma_f32_16x16x32_f16(a0, b, acc2[0][nt], 0, 0, 0);
      acc2[1][nt] = __builtin_amdgcn_mfma_f32_16x16x32_f16(a1, b, acc2[1][nt], 0, 0, 0);
    }
  }
  __syncthreads();   // As reads done -> reuse as Os
#pragma unroll
  for (int mt = 0; mt < 2; ++mt)
#pragma unroll
    for (int nt = 0; nt < 2; ++nt)
#pragma unroll
      for (int r = 0; r < 4; ++r)
        As[mt*16 + quad*4 + r][col0 + nt*16 + m] = __float2half(acc2[mt][nt][r]);
  __syncthreads();
#pragma unroll
  for (int it = 0; it < 2; ++it) {
    int i = tid + it * TPB;
    int r = i >> 4, c = (i & 15) * 8;
    int row = row0 + r;
    if (row < N_NODES)
      *reinterpret_cast<f16x8*>(yout + (size_t)row * DIM + c) =
          *reinterpret_cast<const f16x8*>(&As[r][c]);
  }
}

// ---- gpool: final gather + relu + fire-and-forget atomic pool-sum ----
__global__ __launch_bounds__(TPB) void gpool_k(
    const __half* __restrict__ y, const int* __restrict__ row_ptr2,
    const int* __restrict__ csr_src, const float* __restrict__ bias,
    const int* __restrict__ batch, float* __restrict__ pool_sums) {
  const f16x8* yv = reinterpret_cast<const f16x8*>(y);
  int gid  = blockIdx.x * TPB + threadIdx.x;
  int node = gid / 16;
  int l    = gid % 16;
  if (node >= N_NODES) return;
  int beg = row_ptr2[node * NC];
  int end = row_ptr2[node * NC + NC];

  f16x8 self = yv[(size_t)node * 16 + l];
  float acc[8];
#pragma unroll
  for (int v = 0; v < 8; ++v) acc[v] = (float)self[v];

  int e = beg;
  for (; e + 3 < end; e += 4) {
    int s0 = csr_src[e+0], s1 = csr_src[e+1], s2 = csr_src[e+2], s3 = csr_src[e+3];
    f16x8 v0 = yv[(size_t)s0 * 16 + l];
    f16x8 v1 = yv[(size_t)s1 * 16 + l];
    f16x8 v2 = yv[(size_t)s2 * 16 + l];
    f16x8 v3 = yv[(size_t)s3 * 16 + l];
#pragma unroll
    for (int v = 0; v < 8; ++v)
      acc[v] += ((float)v0[v] + (float)v1[v]) + ((float)v2[v] + (float)v3[v]);
  }
  for (; e < end; ++e) {
    f16x8 v0 = yv[(size_t)csr_src[e] * 16 + l];
#pragma unroll
    for (int v = 0; v < 8; ++v) acc[v] += (float)v0[v];
  }

  float4 b0 = *reinterpret_cast<const float4*>(bias + l * 8);
  float4 b1 = *reinterpret_cast<const float4*>(bias + l * 8 + 4);
  float bb[8] = {b0.x, b0.y, b0.z, b0.w, b1.x, b1.y, b1.z, b1.w};
  int g = batch[node];
  float* ps = pool_sums + (size_t)g * DIM + l * 8;
#pragma unroll
  for (int v = 0; v < 8; ++v)
    atomicAdd(ps + v, fmaxf(acc[v] + bb[v], 0.f));
}

// ---- post: pooled = sums/cnt ; out = relu(pooled @ Wp + bp) ----
__global__ __launch_bounds__(128) void post_k(
    const float* __restrict__ pool_sums, const int* __restrict__ batch,
    const float* __restrict__ W, const float* __restrict__ bias,
    float* __restrict__ out) {
  __shared__ float xs[DIM];
  int g = blockIdx.x;
  int col = threadIdx.x;
  int lo = 0, hi = N_NODES;
  while (lo < hi) { int mid = (lo + hi) >> 1; if (batch[mid] < g) lo = mid + 1; else hi = mid; }
  int beg = lo;
  hi = N_NODES;
  while (lo < hi) { int mid = (lo + hi) >> 1; if (batch[mid] < g + 1) lo = mid + 1; else hi = mid; }
  int end = lo;

  float cnt = fmaxf((float)(end - beg), 1.0f);
  xs[col] = pool_sums[(size_t)g * DIM + col] / cnt;
  __syncthreads();
  float o = bias[col];
  for (int k = 0; k < DIM; ++k)
    o = fmaf(xs[k], W[(size_t)k * DIM + col], o);
  out[(size_t)g * DIM + col] = fmaxf(o, 0.f);
}

extern "C" void kernel_launch(void* const* d_in, const int* in_sizes, int n_in,
                              void* d_out, int out_size, void* d_ws, size_t ws_size,
                              hipStream_t stream) {
  const float* x    = (const float*)d_in[0];
  const int*   ei   = (const int*)d_in[1];
  const int*   batch= (const int*)d_in[2];
  const float* w0 = (const float*)d_in[3];  const float* b0 = (const float*)d_in[4];
  const float* w1 = (const float*)d_in[5];  const float* b1 = (const float*)d_in[6];
  const float* w2 = (const float*)d_in[7];  const float* b2 = (const float*)d_in[8];
  const float* w3 = (const float*)d_in[9];  const float* b3 = (const float*)d_in[10];
  const float* wp = (const float*)d_in[11]; const float* bp = (const float*)d_in[12];
  float* out = (float*)d_out;

  const int* src = ei;
  const int* dst = ei + N_EDGES;

  __half* xh = (__half*)d_ws;
  __half* yA = xh + (size_t)N_NODES * N_FEAT;         // y1, then y3
  __half* yB = yA + (size_t)N_NODES * DIM;            // y2
  __half* Wt0 = yB + (size_t)N_NODES * DIM;
  __half* Wt1 = Wt0 + N_FEAT * DIM;
  __half* Wt2 = Wt1 + DIM * DIM;
  __half* Wt3 = Wt2 + DIM * DIM;
  float* pool_sums = (float*)(Wt3 + DIM * DIM);
  int* cnt2     = (int*)(pool_sums + N_GRAPHS * DIM);
  int* rank     = cnt2 + TOT2;
  int* part     = rank + N_EDGES;
  int* row_ptr2 = part + 256;
  int* csr_src  = row_ptr2 + (TOT2 + 1);

  // ---- CSR build (rank-based, atomic-free fill) ----
  prep_k<<<(PREP_TOTAL + TPB - 1) / TPB, TPB, 0, stream>>>(
      x, xh, w0, w1, w2, w3, Wt0, Wt1, Wt2, Wt3, cnt2, (int*)pool_sums);
  hist_k<<<(N_EDGES + TPB - 1) / TPB, TPB, 0, stream>>>(src, dst, cnt2, rank);
  scan_part_k <<<NBLK, TPB, 0, stream>>>(cnt2, part);
  scan_write_k<<<NBLK, TPB, 0, stream>>>(cnt2, part, row_ptr2);
  fill_k<<<(N_EDGES + TPB - 1) / TPB, TPB, 0, stream>>>(src, dst, row_ptr2,
                                                        rank, csr_src);

  // ---- layer 0+1 fused: gather64 -> h0 = relu(.@W0+b0) -> y1 = h0@W1 ----
  g64gg_k<<<GT32, TPB, 0, stream>>>(xh, row_ptr2, csr_src, Wt0, b0, Wt1, yA);

  // ---- fused gather+gemm: y1 -> y2, y2 -> y3 ----
  fgg_k<<<GT32, TPB, 0, stream>>>(yA, row_ptr2, csr_src, b1, Wt2, yB);
  fgg_k<<<GT32, TPB, 0, stream>>>(yB, row_ptr2, csr_src, b2, Wt3, yA);

  // ---- final gather + pool-sum (atomic), then post-MLP ----
  gpool_k<<<(N_NODES * 16 + TPB - 1) / TPB, TPB, 0, stream>>>(
      yA, row_ptr2, csr_src, b3, batch, pool_sums);
  post_k<<<N_GRAPHS, 128, 0, stream>>>(pool_sums, batch, wp, bp, out);
}

// Round 7
// 255.826 us; speedup vs baseline: 1.7564x; 1.7564x over previous
//
#include <hip/hip_runtime.h>
#include <hip/hip_fp16.h>

// GIN forward, round 20: KEEP g64gg, REVERT gpool. R19's gpool_k atomic
// pool-sum regressed hard (240us: 6.4M fp32 atomics onto 128K addresses
// = ~49-way per-address contention, write-through serialization at LLC).
// Tail restored to R18 form: standalone gather -> h, then pool_post_k
// (33+4us, contention-free). g64gg_k (layer-0 gather fused into the
// first double-GEMM tile) kept -- it was not a hot spot and deletes the
// sb staging round-trip + one dispatch.
// Net structure: R17 CSR build + R18 fgg fusion + R19 g64gg + R18 tail.

#define N_NODES  50000
#define N_EDGES  600000
#define N_FEAT   64
#define DIM      128
#define N_GRAPHS 1024
#define NC       7           // src chunks: src>>13, 0..6
#define CSH      13
#define TOT2     (N_NODES * NC)          // 350000 bins
#define SCH      2048                    // scan elems per block
#define NBLK     ((TOT2 + SCH - 1) / SCH)  // 171
#define TPB      256
#define GT32     ((N_NODES + 31) / 32)     // 1563 fused tiles

typedef _Float16 f16x8 __attribute__((ext_vector_type(8)));
typedef float    f32x4 __attribute__((ext_vector_type(4)));

#define CNTZ2 (TOT2 / 4)                 // 87500 int4 items
#define XWORK (N_NODES * N_FEAT / 4)
#define PREP_TOTAL (CNTZ2 + XWORK + N_FEAT * DIM + 3 * DIM * DIM)

// ---- prep: zero cnt2 ; x->fp16 ; W[K][128] -> Wt[128][K] fp16 ----
__global__ __launch_bounds__(TPB) void prep_k(
    const float* __restrict__ x, __half* __restrict__ xh,
    const float* __restrict__ w0, const float* __restrict__ w1,
    const float* __restrict__ w2, const float* __restrict__ w3,
    __half* __restrict__ Wt0, __half* __restrict__ Wt1,
    __half* __restrict__ Wt2, __half* __restrict__ Wt3,
    int* __restrict__ cnt2) {
  int i = blockIdx.x * TPB + threadIdx.x;
  if (i < CNTZ2) {
    *reinterpret_cast<int4*>(cnt2 + i * 4) = make_int4(0, 0, 0, 0);
    return;
  }
  i -= CNTZ2;
  if (i < XWORK) {
    float4 v = *reinterpret_cast<const float4*>(x + (size_t)i * 4);
    union { __half2 h2[2]; uint2 u; } pk;
    pk.h2[0] = __floats2half2_rn(v.x, v.y);
    pk.h2[1] = __floats2half2_rn(v.z, v.w);
    *reinterpret_cast<uint2*>(xh + (size_t)i * 4) = pk.u;
    return;
  }
  int j = i - XWORK;
  if (j < N_FEAT * DIM) {
    int k = j >> 7, n = j & 127;
    Wt0[n * N_FEAT + k] = __float2half(w0[j]);
    return;
  }
  j -= N_FEAT * DIM;
  if (j >= 3 * DIM * DIM) return;
  int wsel = j / (DIM * DIM);
  int jj = j - wsel * (DIM * DIM);
  int k = jj >> 7, n = jj & 127;
  const float* W = (wsel == 0) ? w1 : (wsel == 1) ? w2 : w3;
  __half* Wt     = (wsel == 0) ? Wt1 : (wsel == 1) ? Wt2 : Wt3;
  Wt[n * DIM + k] = __float2half(W[jj]);
}

// ---- histogram over (dst, src-chunk) keys; rank[e] = old count ----
__global__ __launch_bounds__(TPB) void hist_k(
    const int* __restrict__ src, const int* __restrict__ dst,
    int* __restrict__ cnt2, int* __restrict__ rank) {
  int e = blockIdx.x * TPB + threadIdx.x;
  if (e >= N_EDGES) return;
  int key = dst[e] * NC + (src[e] >> CSH);
  rank[e] = atomicAdd(&cnt2[key], 1);
}

// ---- scan phase 1: per-block (2048 elems) partial sums ----
__global__ __launch_bounds__(TPB) void scan_part_k(
    const int* __restrict__ cnt2, int* __restrict__ part) {
  __shared__ int ws[4];
  int t = threadIdx.x, b = blockIdx.x;
  int base = b * SCH + t * 8;
  int s = 0;
  if (base < TOT2) {    // TOT2 % 8 == 0: all 8 in-bounds together
    int4 a = *reinterpret_cast<const int4*>(cnt2 + base);
    int4 c = *reinterpret_cast<const int4*>(cnt2 + base + 4);
    s = a.x + a.y + a.z + a.w + c.x + c.y + c.z + c.w;
  }
  for (int off = 32; off; off >>= 1) s += __shfl_down(s, off, 64);
  int lane = t & 63, wv = t >> 6;
  if (lane == 0) ws[wv] = s;
  __syncthreads();
  if (t == 0) part[b] = ws[0] + ws[1] + ws[2] + ws[3];
}

// ---- scan phase 2: LDS scan of NBLK partials + intra-block scan-write ----
__global__ __launch_bounds__(TPB) void scan_write_k(
    const int* __restrict__ cnt2, const int* __restrict__ part,
    int* __restrict__ row_ptr2) {
  __shared__ int pscan[TPB];
  __shared__ int wsum[4];
  int t = threadIdx.x, b = blockIdx.x;
  int lane = t & 63, wv = t >> 6;
  int base = b * SCH + t * 8;

  pscan[t] = (t < NBLK) ? part[t] : 0;
  __syncthreads();
  for (int off = 1; off < TPB; off <<= 1) {
    int v = (t >= off) ? pscan[t - off] : 0;
    __syncthreads();
    pscan[t] += v;
    __syncthreads();
  }
  int blk_off = (b > 0) ? pscan[b - 1] : 0;

  int v[8] = {0,0,0,0,0,0,0,0};
  if (base < TOT2) {
    int4 a = *reinterpret_cast<const int4*>(cnt2 + base);
    int4 c = *reinterpret_cast<const int4*>(cnt2 + base + 4);
    v[0]=a.x; v[1]=a.y; v[2]=a.z; v[3]=a.w;
    v[4]=c.x; v[5]=c.y; v[6]=c.z; v[7]=c.w;
  }
  int ls = 0;
#pragma unroll
  for (int i = 0; i < 8; ++i) ls += v[i];
  int incl = ls;
  for (int off = 1; off < 64; off <<= 1) {
    int u = __shfl_up(incl, off, 64);
    if (lane >= off) incl += u;
  }
  if (lane == 63) wsum[wv] = incl;
  __syncthreads();
  int woff = 0;
  for (int w = 0; w < wv; ++w) woff += wsum[w];
  int run = blk_off + woff + (incl - ls);
  if (base < TOT2) {
    int rp[8];
#pragma unroll
    for (int i = 0; i < 8; ++i) { rp[i] = run; run += v[i]; }
    *reinterpret_cast<int4*>(row_ptr2 + base) = make_int4(rp[0], rp[1], rp[2], rp[3]);
    *reinterpret_cast<int4*>(row_ptr2 + base + 4) = make_int4(rp[4], rp[5], rp[6], rp[7]);
  }
  if (b == 0 && t == 0) row_ptr2[TOT2] = N_EDGES;
}

// ---- fill: atomic-free. pos = row_ptr2[key] + rank[e] ----
__global__ __launch_bounds__(TPB) void fill_k(
    const int* __restrict__ src, const int* __restrict__ dst,
    const int* __restrict__ row_ptr2, const int* __restrict__ rank,
    int* __restrict__ csr_src) {
  int e = blockIdx.x * TPB + threadIdx.x;
  if (e >= N_EDGES) return;
  int s = src[e];
  int key = dst[e] * NC + (s >> CSH);
  csr_src[row_ptr2[key] + rank[e]] = s;
}

// ---- g64gg: per 32-row tile: gather64 -> As; h0 = relu(As@W0+b0);
//      y1 = h0@W1. B-fragments straight from L2-hot Wt. LDS 13.3KB. ----
__global__ __launch_bounds__(TPB) void g64gg_k(
    const __half* __restrict__ xh, const int* __restrict__ row_ptr2,
    const int* __restrict__ csr_src,
    const __half* __restrict__ Wt0, const float* __restrict__ b0,
    const __half* __restrict__ Wt1, __half* __restrict__ y1) {
  __shared__ __align__(16) __half As[32][72];   // gathered s tile (K=64)
  __shared__ __align__(16) __half Hs[32][136];  // h0 tile, reused as Os
  const f16x8* xv = reinterpret_cast<const f16x8*>(xh);
  int tid = threadIdx.x;
  int row0 = blockIdx.x * 32;

  // gather phase: 32 node-slots x 8 feature-lanes (64-wide)
  {
    int ns = tid >> 3, l = tid & 7;
    int node = row0 + ns;
    f16x8 o;
    if (node < N_NODES) {
      int beg = row_ptr2[node * NC];
      int end = row_ptr2[node * NC + NC];
      f16x8 self = xv[(size_t)node * 8 + l];
      float acc[8];
#pragma unroll
      for (int v = 0; v < 8; ++v) acc[v] = (float)self[v];
      int e = beg;
      for (; e + 3 < end; e += 4) {
        int s0 = csr_src[e+0], s1 = csr_src[e+1], s2 = csr_src[e+2], s3 = csr_src[e+3];
        f16x8 v0 = xv[(size_t)s0 * 8 + l];
        f16x8 v1 = xv[(size_t)s1 * 8 + l];
        f16x8 v2 = xv[(size_t)s2 * 8 + l];
        f16x8 v3 = xv[(size_t)s3 * 8 + l];
#pragma unroll
        for (int v = 0; v < 8; ++v)
          acc[v] += ((float)v0[v] + (float)v1[v]) + ((float)v2[v] + (float)v3[v]);
      }
      for (; e < end; ++e) {
        f16x8 v0 = xv[(size_t)csr_src[e] * 8 + l];
#pragma unroll
        for (int v = 0; v < 8; ++v) acc[v] += (float)v0[v];
      }
#pragma unroll
      for (int v = 0; v < 8; ++v) o[v] = (_Float16)acc[v];
    } else {
#pragma unroll
      for (int v = 0; v < 8; ++v) o[v] = (_Float16)0.f;
    }
    *reinterpret_cast<f16x8*>(&As[ns][l * 8]) = o;
  }
  __syncthreads();

  int w = tid >> 6, lane = tid & 63;
  int quad = lane >> 4, m = lane & 15;
  int col0 = w * 32;

  // phase A: h0 = relu(As @ W0 + b0)  (K=64)
  f32x4 accA[2][2];
#pragma unroll
  for (int mt = 0; mt < 2; ++mt)
#pragma unroll
    for (int nt = 0; nt < 2; ++nt) accA[mt][nt] = (f32x4){0.f,0.f,0.f,0.f};
#pragma unroll
  for (int kc = 0; kc < 2; ++kc) {
    f16x8 a0 = *reinterpret_cast<const f16x8*>(&As[m][kc*32 + quad*8]);
    f16x8 a1 = *reinterpret_cast<const f16x8*>(&As[16 + m][kc*32 + quad*8]);
#pragma unroll
    for (int nt = 0; nt < 2; ++nt) {
      f16x8 b = *reinterpret_cast<const f16x8*>(
          Wt0 + (size_t)(col0 + nt*16 + m) * N_FEAT + kc*32 + quad*8);
      accA[0][nt] = __builtin_amdgcn_mfma_f32_16x16x32_f16(a0, b, accA[0][nt], 0, 0, 0);
      accA[1][nt] = __builtin_amdgcn_mfma_f32_16x16x32_f16(a1, b, accA[1][nt], 0, 0, 0);
    }
  }
#pragma unroll
  for (int mt = 0; mt < 2; ++mt)
#pragma unroll
    for (int nt = 0; nt < 2; ++nt) {
      float bv = b0[col0 + nt*16 + m];
#pragma unroll
      for (int r = 0; r < 4; ++r)
        Hs[mt*16 + quad*4 + r][col0 + nt*16 + m] =
            __float2half(fmaxf(accA[mt][nt][r] + bv, 0.f));
    }
  __syncthreads();

  // phase B: y1 = Hs @ W1  (K=128)
  f32x4 accB[2][2];
#pragma unroll
  for (int mt = 0; mt < 2; ++mt)
#pragma unroll
    for (int nt = 0; nt < 2; ++nt) accB[mt][nt] = (f32x4){0.f,0.f,0.f,0.f};
#pragma unroll
  for (int kc = 0; kc < 4; ++kc) {
    f16x8 a0 = *reinterpret_cast<const f16x8*>(&Hs[m][kc*32 + quad*8]);
    f16x8 a1 = *reinterpret_cast<const f16x8*>(&Hs[16 + m][kc*32 + quad*8]);
#pragma unroll
    for (int nt = 0; nt < 2; ++nt) {
      f16x8 b = *reinterpret_cast<const f16x8*>(
          Wt1 + (size_t)(col0 + nt*16 + m) * DIM + kc*32 + quad*8);
      accB[0][nt] = __builtin_amdgcn_mfma_f32_16x16x32_f16(a0, b, accB[0][nt], 0, 0, 0);
      accB[1][nt] = __builtin_amdgcn_mfma_f32_16x16x32_f16(a1, b, accB[1][nt], 0, 0, 0);
    }
  }
  __syncthreads();   // Hs reads done -> reuse as Os
#pragma unroll
  for (int mt = 0; mt < 2; ++mt)
#pragma unroll
    for (int nt = 0; nt < 2; ++nt)
#pragma unroll
      for (int r = 0; r < 4; ++r)
        Hs[mt*16 + quad*4 + r][col0 + nt*16 + m] = __float2half(accB[mt][nt][r]);
  __syncthreads();
#pragma unroll
  for (int it = 0; it < 2; ++it) {
    int i = tid + it * TPB;
    int r = i >> 4, c = (i & 15) * 8;
    int row = row0 + r;
    if (row < N_NODES)
      *reinterpret_cast<f16x8*>(y1 + (size_t)row * DIM + c) =
          *reinterpret_cast<const f16x8*>(&Hs[r][c]);
  }
}

// ---- fgg: per 32-row tile: h' = relu(y + agg(y) + b); y' = h' @ Wn ----
__global__ __launch_bounds__(TPB) void fgg_k(
    const __half* __restrict__ y, const int* __restrict__ row_ptr2,
    const int* __restrict__ csr_src, const float* __restrict__ bias,
    const __half* __restrict__ Wn, __half* __restrict__ yout) {
  __shared__ __align__(16) __half As[32][136];  // h' tile, reused as Os
  const f16x8* yv = reinterpret_cast<const f16x8*>(y);
  int tid = threadIdx.x;
  int row0 = blockIdx.x * 32;
  int g = tid >> 4, l = tid & 15;   // 16 node-slots x 16 feature-lanes

#pragma unroll 1
  for (int p = 0; p < 2; ++p) {
    int node = row0 + p * 16 + g;
    if (node < N_NODES) {
      int beg = row_ptr2[node * NC];
      int end = row_ptr2[node * NC + NC];
      f16x8 self = yv[(size_t)node * 16 + l];
      float acc[8];
#pragma unroll
      for (int v = 0; v < 8; ++v) acc[v] = (float)self[v];
      int e = beg;
      for (; e + 3 < end; e += 4) {
        int s0 = csr_src[e+0], s1 = csr_src[e+1], s2 = csr_src[e+2], s3 = csr_src[e+3];
        f16x8 v0 = yv[(size_t)s0 * 16 + l];
        f16x8 v1 = yv[(size_t)s1 * 16 + l];
        f16x8 v2 = yv[(size_t)s2 * 16 + l];
        f16x8 v3 = yv[(size_t)s3 * 16 + l];
#pragma unroll
        for (int v = 0; v < 8; ++v)
          acc[v] += ((float)v0[v] + (float)v1[v]) + ((float)v2[v] + (float)v3[v]);
      }
      for (; e < end; ++e) {
        f16x8 v0 = yv[(size_t)csr_src[e] * 16 + l];
#pragma unroll
        for (int v = 0; v < 8; ++v) acc[v] += (float)v0[v];
      }
      float4 bb0 = *reinterpret_cast<const float4*>(bias + l * 8);
      float4 bb1 = *reinterpret_cast<const float4*>(bias + l * 8 + 4);
      float bb[8] = {bb0.x, bb0.y, bb0.z, bb0.w, bb1.x, bb1.y, bb1.z, bb1.w};
      f16x8 o;
#pragma unroll
      for (int v = 0; v < 8; ++v) o[v] = (_Float16)fmaxf(acc[v] + bb[v], 0.f);
      *reinterpret_cast<f16x8*>(&As[p * 16 + g][l * 8]) = o;
    }
  }
  __syncthreads();

  int w = tid >> 6, lane = tid & 63;
  int quad = lane >> 4, m = lane & 15;
  int col0 = w * 32;
  f32x4 acc2[2][2];
#pragma unroll
  for (int mt = 0; mt < 2; ++mt)
#pragma unroll
    for (int nt = 0; nt < 2; ++nt) acc2[mt][nt] = (f32x4){0.f,0.f,0.f,0.f};
#pragma unroll
  for (int kc = 0; kc < 4; ++kc) {
    f16x8 a0 = *reinterpret_cast<const f16x8*>(&As[m][kc*32 + quad*8]);
    f16x8 a1 = *reinterpret_cast<const f16x8*>(&As[16 + m][kc*32 + quad*8]);
#pragma unroll
    for (int nt = 0; nt < 2; ++nt) {
      f16x8 b = *reinterpret_cast<const f16x8*>(
          Wn + (size_t)(col0 + nt*16 + m) * DIM + kc*32 + quad*8);
      acc2[0][nt] = __builtin_amdgcn_mfma_f32_16x16x32_f16(a0, b, acc2[0][nt], 0, 0, 0);
      acc2[1][nt] = __builtin_amdgcn_mfma_f32_16x16x32_f16(a1, b, acc2[1][nt], 0, 0, 0);
    }
  }
  __syncthreads();   // As reads done -> reuse as Os
#pragma unroll
  for (int mt = 0; mt < 2; ++mt)
#pragma unroll
    for (int nt = 0; nt < 2; ++nt)
#pragma unroll
      for (int r = 0; r < 4; ++r)
        As[mt*16 + quad*4 + r][col0 + nt*16 + m] = __float2half(acc2[mt][nt][r]);
  __syncthreads();
#pragma unroll
  for (int it = 0; it < 2; ++it) {
    int i = tid + it * TPB;
    int r = i >> 4, c = (i & 15) * 8;
    int row = row0 + r;
    if (row < N_NODES)
      *reinterpret_cast<f16x8*>(yout + (size_t)row * DIM + c) =
          *reinterpret_cast<const f16x8*>(&As[r][c]);
  }
}

// ---- standalone gather (R13 shape): 16 lanes/node, 4-deep unroll ----
template<int F, bool BR>
__global__ __launch_bounds__(TPB) void gather_k(
    const __half* __restrict__ y, const int* __restrict__ row_ptr2,
    const int* __restrict__ csr_src, const float* __restrict__ bias,
    __half* __restrict__ hout) {
  constexpr int CH = F / 8;
  const f16x8* yv = reinterpret_cast<const f16x8*>(y);
  int gid  = blockIdx.x * TPB + threadIdx.x;
  int node = gid / CH;
  int l    = gid % CH;
  if (node >= N_NODES) return;
  int beg = row_ptr2[node * NC];
  int end = row_ptr2[node * NC + NC];

  f16x8 self = yv[(size_t)node * CH + l];
  float acc[8];
#pragma unroll
  for (int v = 0; v < 8; ++v) acc[v] = (float)self[v];

  int e = beg;
  for (; e + 3 < end; e += 4) {
    int s0 = csr_src[e+0], s1 = csr_src[e+1], s2 = csr_src[e+2], s3 = csr_src[e+3];
    f16x8 v0 = yv[(size_t)s0 * CH + l];
    f16x8 v1 = yv[(size_t)s1 * CH + l];
    f16x8 v2 = yv[(size_t)s2 * CH + l];
    f16x8 v3 = yv[(size_t)s3 * CH + l];
#pragma unroll
    for (int v = 0; v < 8; ++v)
      acc[v] += ((float)v0[v] + (float)v1[v]) + ((float)v2[v] + (float)v3[v]);
  }
  for (; e < end; ++e) {
    f16x8 v0 = yv[(size_t)csr_src[e] * CH + l];
#pragma unroll
    for (int v = 0; v < 8; ++v) acc[v] += (float)v0[v];
  }

  f16x8 o;
  if (BR) {
    float4 b0 = *reinterpret_cast<const float4*>(bias + l * 8);
    float4 b1 = *reinterpret_cast<const float4*>(bias + l * 8 + 4);
    float bb[8] = {b0.x, b0.y, b0.z, b0.w, b1.x, b1.y, b1.z, b1.w};
#pragma unroll
    for (int v = 0; v < 8; ++v) o[v] = (_Float16)fmaxf(acc[v] + bb[v], 0.f);
  } else {
#pragma unroll
    for (int v = 0; v < 8; ++v) o[v] = (_Float16)acc[v];
  }
  reinterpret_cast<f16x8*>(hout)[(size_t)node * CH + l] = o;
}

// ---- fused mean-pool (sorted batch) + post-MLP (fp32) ----
__global__ __launch_bounds__(128) void pool_post_k(
    const __half* __restrict__ h, const int* __restrict__ batch,
    const float* __restrict__ W, const float* __restrict__ bias,
    float* __restrict__ out) {
  __shared__ float xs[DIM];
  int g = blockIdx.x;
  int col = threadIdx.x;
  int lo = 0, hi = N_NODES;
  while (lo < hi) { int mid = (lo + hi) >> 1; if (batch[mid] < g) lo = mid + 1; else hi = mid; }
  int beg = lo;
  hi = N_NODES;
  while (lo < hi) { int mid = (lo + hi) >> 1; if (batch[mid] < g + 1) lo = mid + 1; else hi = mid; }
  int end = lo;

  float acc = 0.f;
  for (int n = beg; n < end; ++n) acc += __half2float(h[(size_t)n * DIM + col]);
  float cnt = fmaxf((float)(end - beg), 1.0f);
  xs[col] = acc / cnt;
  __syncthreads();
  float o = bias[col];
  for (int k = 0; k < DIM; ++k)
    o = fmaf(xs[k], W[(size_t)k * DIM + col], o);
  out[(size_t)g * DIM + col] = fmaxf(o, 0.f);
}

extern "C" void kernel_launch(void* const* d_in, const int* in_sizes, int n_in,
                              void* d_out, int out_size, void* d_ws, size_t ws_size,
                              hipStream_t stream) {
  const float* x    = (const float*)d_in[0];
  const int*   ei   = (const int*)d_in[1];
  const int*   batch= (const int*)d_in[2];
  const float* w0 = (const float*)d_in[3];  const float* b0 = (const float*)d_in[4];
  const float* w1 = (const float*)d_in[5];  const float* b1 = (const float*)d_in[6];
  const float* w2 = (const float*)d_in[7];  const float* b2 = (const float*)d_in[8];
  const float* w3 = (const float*)d_in[9];  const float* b3 = (const float*)d_in[10];
  const float* wp = (const float*)d_in[11]; const float* bp = (const float*)d_in[12];
  float* out = (float*)d_out;

  const int* src = ei;
  const int* dst = ei + N_EDGES;

  __half* xh = (__half*)d_ws;
  __half* yA = xh + (size_t)N_NODES * N_FEAT;         // y1, then y3
  __half* yB = yA + (size_t)N_NODES * DIM;            // y2
  __half* h  = yB + (size_t)N_NODES * DIM;            // final h3
  __half* Wt0 = h + (size_t)N_NODES * DIM;
  __half* Wt1 = Wt0 + N_FEAT * DIM;
  __half* Wt2 = Wt1 + DIM * DIM;
  __half* Wt3 = Wt2 + DIM * DIM;
  int* cnt2     = (int*)(Wt3 + DIM * DIM);
  int* rank     = cnt2 + TOT2;
  int* part     = rank + N_EDGES;
  int* row_ptr2 = part + 256;
  int* csr_src  = row_ptr2 + (TOT2 + 1);

  // ---- CSR build (rank-based, atomic-free fill) ----
  prep_k<<<(PREP_TOTAL + TPB - 1) / TPB, TPB, 0, stream>>>(
      x, xh, w0, w1, w2, w3, Wt0, Wt1, Wt2, Wt3, cnt2);
  hist_k<<<(N_EDGES + TPB - 1) / TPB, TPB, 0, stream>>>(src, dst, cnt2, rank);
  scan_part_k <<<NBLK, TPB, 0, stream>>>(cnt2, part);
  scan_write_k<<<NBLK, TPB, 0, stream>>>(cnt2, part, row_ptr2);
  fill_k<<<(N_EDGES + TPB - 1) / TPB, TPB, 0, stream>>>(src, dst, row_ptr2,
                                                        rank, csr_src);

  // ---- layer 0+1 fused: gather64 -> h0 = relu(.@W0+b0) -> y1 = h0@W1 ----
  g64gg_k<<<GT32, TPB, 0, stream>>>(xh, row_ptr2, csr_src, Wt0, b0, Wt1, yA);

  // ---- fused gather+gemm: y1 -> y2, y2 -> y3 ----
  fgg_k<<<GT32, TPB, 0, stream>>>(yA, row_ptr2, csr_src, b1, Wt2, yB);
  fgg_k<<<GT32, TPB, 0, stream>>>(yB, row_ptr2, csr_src, b2, Wt3, yA);

  // ---- final gather: h3 = relu(y3 + agg(y3) + b3) ----
  gather_k<DIM, true><<<(N_NODES * 16 + TPB - 1) / TPB, TPB, 0, stream>>>(
      yA, row_ptr2, csr_src, b3, h);

  // ---- pool + post-MLP ----
  pool_post_k<<<N_GRAPHS, 128, 0, stream>>>(h, batch, wp, bp, out);
}